// Round 1
// baseline (164.195 us; speedup 1.0000x reference)
//
#include <hip/hip_runtime.h>
#include <hip/hip_bf16.h>
#include <stdint.h>

#define OUTN 4096
#define INN  4096
#define SPECN 512

typedef __attribute__((ext_vector_type(8))) short short8;
typedef __attribute__((ext_vector_type(4))) float f32x4;

__device__ __forceinline__ ushort f2bf(float f) {
    uint32_t u = __float_as_uint(f);
    uint32_t r = (u + 0x7FFFu + ((u >> 16) & 1u)) >> 16;
    return (ushort)r;
}

// ---------------------------------------------------------------------------
// Kernel 1: build A1 (weight-coefficient matrix), A2 (simplex-coefficient
// matrix) in bf16, and the ubias output (row reduction). One block per s-row.
// ---------------------------------------------------------------------------
__global__ __launch_bounds__(256) void build_A(
    const float* __restrict__ uA, const float* __restrict__ Lb,
    const float* __restrict__ Ub, const float* __restrict__ Bias,
    const float* __restrict__ Alpha, ushort* __restrict__ A1,
    ushort* __restrict__ A2, float* __restrict__ ubias_out)
{
    const int s = blockIdx.x;
    const int tid = threadIdx.x;
    float acc = 0.f;

    for (int p = 0; p < 4; ++p) {
        const int o = p * 1024 + tid * 4;
        const float4 u4 = *(const float4*)&uA[(size_t)s * OUTN + o];
        const float4 lb4 = *(const float4*)&Lb[o];
        const float4 ub4 = *(const float4*)&Ub[o];
        const float4 b4 = *(const float4*)&Bias[o];
        const float4 a4 = *(const float4*)&Alpha[o];
        const float uu[4] = {u4.x, u4.y, u4.z, u4.w};
        const float lbv[4] = {lb4.x, lb4.y, lb4.z, lb4.w};
        const float ubv[4] = {ub4.x, ub4.y, ub4.z, ub4.w};
        const float bv[4] = {b4.x, b4.y, b4.z, b4.w};
        const float av[4] = {a4.x, a4.y, a4.z, a4.w};
        ushort r1[4], r2[4];
#pragma unroll
        for (int j = 0; j < 4; ++j) {
            const float u = uu[j], lb = lbv[j], ub = ubv[j], b = bv[j], a = av[j];
            const float pp = fmaxf(u, 0.f), nn = fminf(u, 0.f);
            const bool stneg = (ub <= 0.f);
            const bool stpos = (lb >= 0.f);
            const float lower_d = (fabsf(lb) >= fabsf(ub)) ? 1.f : 0.f;
            float lbr = fminf(lb, 0.f);
            float ubr = fmaxf(ub, 0.f);
            ubr = fmaxf(ubr, lbr + 1e-8f);
            const float ud = ubr / (ubr - lbr);
            const float upb = -lbr * ud;
            const float ldc = (ud > 0.5f) ? 1.f : 0.f;
            const float oma = 1.f - a;
            const float crown = ud * pp + ldc * nn;
            const float wcoef = a * crown +
                oma * (stneg ? 0.f : (stpos ? (pp + nn) : lower_d * nn));
            const float scoef = (stneg || stpos) ? 0.f : oma * pp;
            const float ub_t = stneg ? 0.f : (stpos ? b : fmaxf(b, 0.f));
            const float lb_t = stneg ? 0.f : (stpos ? b : lower_d * b);
            acc += pp * (oma * ub_t + upb) + nn * (oma * lb_t) + crown * (a * b);
            r1[j] = f2bf(wcoef);
            r2[j] = f2bf(scoef);
        }
        *(ushort4*)&A1[(size_t)s * OUTN + o] = make_ushort4(r1[0], r1[1], r1[2], r1[3]);
        *(ushort4*)&A2[(size_t)s * OUTN + o] = make_ushort4(r2[0], r2[1], r2[2], r2[3]);
    }

    // block reduction for ubias
#pragma unroll
    for (int off = 32; off > 0; off >>= 1) acc += __shfl_down(acc, off);
    __shared__ float red[4];
    if ((tid & 63) == 0) red[tid >> 6] = acc;
    __syncthreads();
    if (tid == 0) ubias_out[s] = red[0] + red[1] + red[2] + red[3];
}

// ---------------------------------------------------------------------------
// Kernel 2: per-64-column-block flags: does A2 have any nonzero in this
// K-block? (Lets the GEMM skip the simplex matmul when alpha==1.)
// ---------------------------------------------------------------------------
__global__ __launch_bounds__(256) void make_flags(
    const ushort* __restrict__ A2, int* __restrict__ flags)
{
    const int b = blockIdx.x;       // 64 blocks
    const int tid = threadIdx.x;
    const int c0 = b * 64 + (tid & 15) * 4;
    const int rbase = tid >> 4;     // 0..15
    int any = 0;
    for (int k = 0; k < 32; ++k) {
        const int r = rbase + k * 16;
        const ushort4 v = *(const ushort4*)&A2[(size_t)r * OUTN + c0];
        any |= (v.x & 0x7FFF) | (v.y & 0x7FFF) | (v.z & 0x7FFF) | (v.w & 0x7FFF);
    }
    __shared__ int f;
    if (tid == 0) f = 0;
    __syncthreads();
    if (__any(any != 0) && (tid & 63) == 0) atomicOr(&f, 1);
    __syncthreads();
    if (tid == 0) flags[b] = f;
}

// ---------------------------------------------------------------------------
// Kernel 3: transpose + convert W (f32, [o][i]) -> WT (bf16, [i][o]) so the
// GEMM B-operand is K-contiguous. If the flag for this o-block is set, also
// produce ST = relu(W + bias) - relu(bias) transposed.
// ---------------------------------------------------------------------------
__global__ __launch_bounds__(256) void transpose_w(
    const float* __restrict__ W, const float* __restrict__ Bias,
    const int* __restrict__ flags, ushort* __restrict__ WT,
    ushort* __restrict__ ST)
{
    __shared__ float t[64][65];     // pad to 65 to avoid bank conflicts
    const int bi = blockIdx.x & 63;
    const int bo = blockIdx.x >> 6;
    const int i0 = bi * 64, o0 = bo * 64;
    const int tid = threadIdx.x;
    const bool needS = (flags[bo] != 0);
    const int sub = tid >> 4;         // 0..15
    const int q4 = (tid & 15) * 4;    // 0..60

#pragma unroll
    for (int p = 0; p < 4; ++p) {
        const int ol = p * 16 + sub;
        const float4 w = *(const float4*)&W[(size_t)(o0 + ol) * INN + i0 + q4];
        t[q4 + 0][ol] = w.x;
        t[q4 + 1][ol] = w.y;
        t[q4 + 2][ol] = w.z;
        t[q4 + 3][ol] = w.w;
    }
    __syncthreads();
#pragma unroll
    for (int p = 0; p < 4; ++p) {
        const int il = p * 16 + sub;
        const float w0 = t[il][q4], w1 = t[il][q4 + 1];
        const float w2 = t[il][q4 + 2], w3 = t[il][q4 + 3];
        *(ushort4*)&WT[(size_t)(i0 + il) * OUTN + o0 + q4] =
            make_ushort4(f2bf(w0), f2bf(w1), f2bf(w2), f2bf(w3));
        if (needS) {
            const float4 b4 = *(const float4*)&Bias[o0 + q4];
            const float s0 = fmaxf(w0 + b4.x, 0.f) - fmaxf(b4.x, 0.f);
            const float s1 = fmaxf(w1 + b4.y, 0.f) - fmaxf(b4.y, 0.f);
            const float s2 = fmaxf(w2 + b4.z, 0.f) - fmaxf(b4.z, 0.f);
            const float s3 = fmaxf(w3 + b4.w, 0.f) - fmaxf(b4.w, 0.f);
            *(ushort4*)&ST[(size_t)(i0 + il) * OUTN + o0 + q4] =
                make_ushort4(f2bf(s0), f2bf(s1), f2bf(s2), f2bf(s3));
        }
    }
}

// ---------------------------------------------------------------------------
// Kernel 4: bf16 MFMA GEMM. uA[s,i] = A1[s,:]·WT[i,:] (+ A2·ST when flagged).
// BM=BN=BK=64, 256 threads (4 waves, each a 32x32 sub-tile of C).
// LDS staged via global_load_lds width-16 with XOR-swizzled global source
// (chunk ^= row&7) so ds_read_b128 fragment reads are conflict-free.
// ---------------------------------------------------------------------------
__global__ __launch_bounds__(256) void gemm(
    const ushort* __restrict__ A1, const ushort* __restrict__ A2,
    const ushort* __restrict__ WT, const ushort* __restrict__ ST,
    const int* __restrict__ flags, float* __restrict__ outp)
{
    __shared__ ushort sA1[64 * 64];
    __shared__ ushort sB[64 * 64];
    __shared__ ushort sA2[64 * 64];
    __shared__ ushort sS[64 * 64];

    const int bx = blockIdx.x & 63;   // i tile (0..63)
    const int by = blockIdx.x >> 6;   // s tile (0..7)
    const int i0 = bx * 64, s0 = by * 64;
    const int tid = threadIdx.x;
    const int lane = tid & 63;
    const int w = tid >> 6;
    const int wr = w >> 1, wc = w & 1;

    f32x4 acc[2][2] = {};

    // staging geometry: 8 chunks of 1KB per 8KB buffer; wave w does chunks
    // 2w, 2w+1. chunk c covers rows c*8..c*8+8; lane l -> row c*8 + l/8,
    // 16B-column (l%8) which must hold global column ((l%8) ^ (row&7)).
    const int rA[2] = { (w * 2 + 0) * 8 + (lane >> 3), (w * 2 + 1) * 8 + (lane >> 3) };
    const int gcol[2] = { (lane & 7) ^ (rA[0] & 7), (lane & 7) ^ (rA[1] & 7) };

    for (int ko = 0; ko < OUTN; ko += 64) {
        const bool useS = (flags[ko >> 6] != 0);
#pragma unroll
        for (int h = 0; h < 2; ++h) {
            const int c = w * 2 + h;
            const int r = rA[h];
            const size_t goff = (size_t)ko + gcol[h] * 8;   // in ushorts
            __builtin_amdgcn_global_load_lds(
                (const __attribute__((address_space(1))) void*)(A1 + (size_t)(s0 + r) * OUTN + goff),
                (__attribute__((address_space(3))) void*)&sA1[c * 512], 16, 0, 0);
            __builtin_amdgcn_global_load_lds(
                (const __attribute__((address_space(1))) void*)(WT + (size_t)(i0 + r) * OUTN + goff),
                (__attribute__((address_space(3))) void*)&sB[c * 512], 16, 0, 0);
            if (useS) {
                __builtin_amdgcn_global_load_lds(
                    (const __attribute__((address_space(1))) void*)(A2 + (size_t)(s0 + r) * OUTN + goff),
                    (__attribute__((address_space(3))) void*)&sA2[c * 512], 16, 0, 0);
                __builtin_amdgcn_global_load_lds(
                    (const __attribute__((address_space(1))) void*)(ST + (size_t)(i0 + r) * OUTN + goff),
                    (__attribute__((address_space(3))) void*)&sS[c * 512], 16, 0, 0);
            }
        }
        __syncthreads();

#pragma unroll
        for (int kk = 0; kk < 64; kk += 32) {
            short8 av[2], bv[2];
#pragma unroll
            for (int m = 0; m < 2; ++m) {
                const int r = wr * 32 + m * 16 + (lane & 15);
                const int g = ((kk >> 3) + (lane >> 4)) ^ (r & 7);
                av[m] = *(const short8*)&sA1[r * 64 + g * 8];
            }
#pragma unroll
            for (int n = 0; n < 2; ++n) {
                const int r = wc * 32 + n * 16 + (lane & 15);
                const int g = ((kk >> 3) + (lane >> 4)) ^ (r & 7);
                bv[n] = *(const short8*)&sB[r * 64 + g * 8];
            }
#pragma unroll
            for (int m = 0; m < 2; ++m)
#pragma unroll
                for (int n = 0; n < 2; ++n)
                    acc[m][n] = __builtin_amdgcn_mfma_f32_16x16x32_bf16(
                        av[m], bv[n], acc[m][n], 0, 0, 0);
            if (useS) {
                short8 av2[2], bv2[2];
#pragma unroll
                for (int m = 0; m < 2; ++m) {
                    const int r = wr * 32 + m * 16 + (lane & 15);
                    const int g = ((kk >> 3) + (lane >> 4)) ^ (r & 7);
                    av2[m] = *(const short8*)&sA2[r * 64 + g * 8];
                }
#pragma unroll
                for (int n = 0; n < 2; ++n) {
                    const int r = wc * 32 + n * 16 + (lane & 15);
                    const int g = ((kk >> 3) + (lane >> 4)) ^ (r & 7);
                    bv2[n] = *(const short8*)&sS[r * 64 + g * 8];
                }
#pragma unroll
                for (int m = 0; m < 2; ++m)
#pragma unroll
                    for (int n = 0; n < 2; ++n)
                        acc[m][n] = __builtin_amdgcn_mfma_f32_16x16x32_bf16(
                            av2[m], bv2[n], acc[m][n], 0, 0, 0);
            }
        }
        __syncthreads();
    }

    // C/D layout: col = lane&15, row = (lane>>4)*4 + reg   [m89/m91 verified]
#pragma unroll
    for (int m = 0; m < 2; ++m)
#pragma unroll
        for (int n = 0; n < 2; ++n) {
            const int srow = s0 + wr * 32 + m * 16 + (lane >> 4) * 4;
            const int icol = i0 + wc * 32 + n * 16 + (lane & 15);
#pragma unroll
            for (int r = 0; r < 4; ++r)
                outp[(size_t)(srow + r) * INN + icol] = acc[m][n][r];
        }
}

// ---------------------------------------------------------------------------
extern "C" void kernel_launch(void* const* d_in, const int* in_sizes, int n_in,
                              void* d_out, int out_size, void* d_ws, size_t ws_size,
                              hipStream_t stream) {
    const float* uA    = (const float*)d_in[0];
    const float* W     = (const float*)d_in[1];
    const float* Bias  = (const float*)d_in[2];
    const float* Lb    = (const float*)d_in[3];
    const float* Ub    = (const float*)d_in[4];
    const float* Alpha = (const float*)d_in[5];
    float* outp = (float*)d_out;

    char* ws = (char*)d_ws;
    int*    flags = (int*)ws;                                    // 64 ints
    ushort* A1 = (ushort*)(ws + 4096);                           // 4 MB
    ushort* A2 = (ushort*)(ws + 4096 + (1u << 22));              // 4 MB
    ushort* WT = (ushort*)(ws + 4096 + (2u << 22));              // 32 MB
    ushort* ST = (ushort*)(ws + 4096 + (2u << 22) + (1u << 25)); // 32 MB (cond.)

    build_A<<<512, 256, 0, stream>>>(uA, Lb, Ub, Bias, Alpha, A1, A2,
                                     outp + (size_t)SPECN * INN);
    make_flags<<<64, 256, 0, stream>>>(A2, flags);
    transpose_w<<<4096, 256, 0, stream>>>(W, Bias, flags, WT, ST);
    gemm<<<512, 256, 0, stream>>>(A1, A2, WT, ST, flags, outp);
}

// Round 3
// 146.639 us; speedup vs baseline: 1.1197x; 1.1197x over previous
//
#include <hip/hip_runtime.h>
#include <hip/hip_bf16.h>
#include <stdint.h>

#define OUTN 4096
#define INN  4096
#define SPECN 512
#define BK 128
#define KT (OUTN / BK)   // 32

typedef __attribute__((ext_vector_type(8))) short short8;
typedef __attribute__((ext_vector_type(4))) float f32x4;

__device__ __forceinline__ ushort f2bf(float f) {
    uint32_t u = __float_as_uint(f);
    uint32_t r = (u + 0x7FFFu + ((u >> 16) & 1u)) >> 16;
    return (ushort)r;
}
__device__ __forceinline__ float bf2f(ushort u) {
    return __uint_as_float((uint32_t)u << 16);
}

// ---------------------------------------------------------------------------
// prep: blocks [0,512) build A1/A2 (bf16) + ubias + rowmask (bitmask of
// k-blocks with nonzero simplex coeff, per s-row, no atomics).
// Blocks [512, 4608) transpose+convert W (f32 [o][i]) -> WT (bf16 [i][o]).
// ---------------------------------------------------------------------------
__global__ __launch_bounds__(256) void prep(
    const float* __restrict__ uA, const float* __restrict__ W,
    const float* __restrict__ Bias, const float* __restrict__ Lb,
    const float* __restrict__ Ub, const float* __restrict__ Alpha,
    ushort* __restrict__ A1, ushort* __restrict__ A2, ushort* __restrict__ WT,
    unsigned long long* __restrict__ rowmask, float* __restrict__ ubias_out)
{
    const int tid = threadIdx.x;
    if (blockIdx.x < 512) {
        // ----- build path -----
        const int s = blockIdx.x;
        float acc = 0.f;
        unsigned long long msk = 0;
        for (int p = 0; p < 4; ++p) {
            const int o = p * 1024 + tid * 4;
            const float4 u4 = *(const float4*)&uA[(size_t)s * OUTN + o];
            const float4 lb4 = *(const float4*)&Lb[o];
            const float4 ub4 = *(const float4*)&Ub[o];
            const float4 b4 = *(const float4*)&Bias[o];
            const float4 a4 = *(const float4*)&Alpha[o];
            const float uu[4] = {u4.x, u4.y, u4.z, u4.w};
            const float lbv[4] = {lb4.x, lb4.y, lb4.z, lb4.w};
            const float ubv[4] = {ub4.x, ub4.y, ub4.z, ub4.w};
            const float bv[4] = {b4.x, b4.y, b4.z, b4.w};
            const float av[4] = {a4.x, a4.y, a4.z, a4.w};
            ushort r1[4], r2[4];
#pragma unroll
            for (int j = 0; j < 4; ++j) {
                const float u = uu[j], lb = lbv[j], ub = ubv[j], b = bv[j], a = av[j];
                const float pp = fmaxf(u, 0.f), nn = fminf(u, 0.f);
                const bool stneg = (ub <= 0.f);
                const bool stpos = (lb >= 0.f);
                const float lower_d = (fabsf(lb) >= fabsf(ub)) ? 1.f : 0.f;
                float lbr = fminf(lb, 0.f);
                float ubr = fmaxf(ub, 0.f);
                ubr = fmaxf(ubr, lbr + 1e-8f);
                const float ud = ubr / (ubr - lbr);
                const float upb = -lbr * ud;
                const float ldc = (ud > 0.5f) ? 1.f : 0.f;
                const float oma = 1.f - a;
                const float crown = ud * pp + ldc * nn;
                const float wcoef = a * crown +
                    oma * (stneg ? 0.f : (stpos ? (pp + nn) : lower_d * nn));
                const float scoef = (stneg || stpos) ? 0.f : oma * pp;
                const float ub_t = stneg ? 0.f : (stpos ? b : fmaxf(b, 0.f));
                const float lb_t = stneg ? 0.f : (stpos ? b : lower_d * b);
                acc += pp * (oma * ub_t + upb) + nn * (oma * lb_t) + crown * (a * b);
                r1[j] = f2bf(wcoef);
                r2[j] = f2bf(scoef);
            }
            *(ushort4*)&A1[(size_t)s * OUTN + o] = make_ushort4(r1[0], r1[1], r1[2], r1[3]);
            *(ushort4*)&A2[(size_t)s * OUTN + o] = make_ushort4(r2[0], r2[1], r2[2], r2[3]);
            if (((r2[0] | r2[1] | r2[2] | r2[3]) & 0x7FFF) != 0)
                msk |= 1ull << (p * 16 + (tid >> 4));
        }
#pragma unroll
        for (int off = 32; off; off >>= 1) {
            acc += __shfl_down(acc, off);
            msk |= __shfl_down(msk, off);
        }
        __shared__ float redf[4];
        __shared__ unsigned long long redm[4];
        if ((tid & 63) == 0) { redf[tid >> 6] = acc; redm[tid >> 6] = msk; }
        __syncthreads();
        if (tid == 0) {
            ubias_out[s] = redf[0] + redf[1] + redf[2] + redf[3];
            rowmask[s] = redm[0] | redm[1] | redm[2] | redm[3];
        }
    } else {
        // ----- transpose path -----
        __shared__ float t[64][65];
        const int tb = blockIdx.x - 512;
        const int bi = tb & 63, bo = tb >> 6;
        const int i0 = bi * 64, o0 = bo * 64;
        const int sub = tid >> 4;        // 0..15
        const int q4 = (tid & 15) * 4;   // 0..60
#pragma unroll
        for (int p = 0; p < 4; ++p) {
            const int ol = p * 16 + sub;
            const float4 w = *(const float4*)&W[(size_t)(o0 + ol) * INN + i0 + q4];
            t[q4 + 0][ol] = w.x;
            t[q4 + 1][ol] = w.y;
            t[q4 + 2][ol] = w.z;
            t[q4 + 3][ol] = w.w;
        }
        __syncthreads();
#pragma unroll
        for (int p = 0; p < 4; ++p) {
            const int il = p * 16 + sub;
            *(ushort4*)&WT[(size_t)(i0 + il) * OUTN + o0 + q4] =
                make_ushort4(f2bf(t[il][q4]), f2bf(t[il][q4 + 1]),
                             f2bf(t[il][q4 + 2]), f2bf(t[il][q4 + 3]));
        }
    }
}

// ---------------------------------------------------------------------------
// gemm: uA[s,i] = A1[s,:]·WT[i,:] (+ A2·S^T on flagged k-blocks, S computed
// on the fly). BM=BN=64, BK=128, 2-phase pipelined (stage next || compute
// current, ONE barrier per K-step). Source-swizzled global_load_lds
// (chunk ^= row&15) keeps ds_read_b128 fragment reads conflict-free.
// ---------------------------------------------------------------------------
__global__ __launch_bounds__(256) void gemm(
    const ushort* __restrict__ A1, const ushort* __restrict__ A2,
    const ushort* __restrict__ WT, const float* __restrict__ Bias,
    const unsigned long long* __restrict__ rowmask, float* __restrict__ outp)
{
    __shared__ ushort sA[2][64 * BK];
    __shared__ ushort sB[2][64 * BK];
    __shared__ unsigned long long smaskLds;

    // bx-major so 8 consecutive blocks share a WT panel; XCD-chunked swizzle.
    const int bid = blockIdx.x;
    const int swz = (bid & 7) * 64 + (bid >> 3);
    const int bx = swz >> 3;   // i tile 0..63
    const int by = swz & 7;    // s tile 0..7
    const int i0 = bx * 64, s0 = by * 64;
    const int tid = threadIdx.x;
    const int lane = tid & 63;
    const int w = tid >> 6;
    const int wr = w >> 1, wc = w & 1;

    if (tid < 64) {
        unsigned long long v = rowmask[s0 + tid];
#pragma unroll
        for (int off = 32; off; off >>= 1) v |= __shfl_down(v, off);
        if (tid == 0) smaskLds = v;
    }

    f32x4 acc[2][2] = {};

    // main-loop staging: 16 chunks of 1KB per 16KB tile; wave w does 4.
    // chunk c covers rows c*4..c*4+3; lane l -> row c*4 + (l>>4), 16B-pos
    // l&15, which must hold global 16B-chunk ((l&15) ^ (row&15)).
    auto stage = [&](int buf, int t) {
        const int ko = t * BK;
#pragma unroll
        for (int h = 0; h < 4; ++h) {
            const int c = w * 4 + h;
            const int r = c * 4 + (lane >> 4);
            const int g = (lane & 15) ^ (r & 15);
            const size_t off = (size_t)ko + g * 8;
            __builtin_amdgcn_global_load_lds(
                (const __attribute__((address_space(1))) void*)(A1 + (size_t)(s0 + r) * OUTN + off),
                (__attribute__((address_space(3))) void*)&sA[buf][c * 512], 16, 0, 0);
            __builtin_amdgcn_global_load_lds(
                (const __attribute__((address_space(1))) void*)(WT + (size_t)(i0 + r) * OUTN + off),
                (__attribute__((address_space(3))) void*)&sB[buf][c * 512], 16, 0, 0);
        }
    };

    auto compute = [&](int buf) {
#pragma unroll
        for (int kk = 0; kk < BK; kk += 32) {
            short8 av[2], bv[2];
#pragma unroll
            for (int m = 0; m < 2; ++m) {
                const int r = wr * 32 + m * 16 + (lane & 15);
                const int g = ((kk >> 3) + (lane >> 4)) ^ (r & 15);
                av[m] = *(const short8*)&sA[buf][r * BK + g * 8];
            }
#pragma unroll
            for (int n = 0; n < 2; ++n) {
                const int r = wc * 32 + n * 16 + (lane & 15);
                const int g = ((kk >> 3) + (lane >> 4)) ^ (r & 15);
                bv[n] = *(const short8*)&sB[buf][r * BK + g * 8];
            }
#pragma unroll
            for (int m = 0; m < 2; ++m)
#pragma unroll
                for (int n = 0; n < 2; ++n)
                    acc[m][n] = __builtin_amdgcn_mfma_f32_16x16x32_bf16(
                        av[m], bv[n], acc[m][n], 0, 0, 0);
        }
    };

    stage(0, 0);
    __syncthreads();
    const unsigned long long smask = smaskLds;
    for (int t = 0; t < KT - 1; ++t) {
        stage((t + 1) & 1, t + 1);      // prefetch next K-tile
        compute(t & 1);                 // MFMA on current (hides the loads)
        __syncthreads();                // vmcnt(0)+lgkmcnt(0)+barrier
    }
    compute((KT - 1) & 1);

    // rare path: simplex contribution for flagged 64-wide k-blocks.
    if (smask) {
        for (int b = 0; b < 64; ++b) {
            if (!((smask >> b) & 1)) continue;
            __syncthreads();            // buffers free to overwrite
#pragma unroll
            for (int h = 0; h < 2; ++h) {
                const int c = w * 2 + h;
                const int r = c * 8 + (lane >> 3);
                const int g = (lane & 7) ^ (r & 7);
                const size_t off = (size_t)b * 64 + g * 8;
                __builtin_amdgcn_global_load_lds(
                    (const __attribute__((address_space(1))) void*)(A2 + (size_t)(s0 + r) * OUTN + off),
                    (__attribute__((address_space(3))) void*)&sA[0][c * 512], 16, 0, 0);
                __builtin_amdgcn_global_load_lds(
                    (const __attribute__((address_space(1))) void*)(WT + (size_t)(i0 + r) * OUTN + off),
                    (__attribute__((address_space(3))) void*)&sB[0][c * 512], 16, 0, 0);
            }
            __syncthreads();
#pragma unroll
            for (int kk = 0; kk < 64; kk += 32) {
                short8 av2[2], bw[2];
#pragma unroll
                for (int m = 0; m < 2; ++m) {
                    const int r = wr * 32 + m * 16 + (lane & 15);
                    const int g = ((kk >> 3) + (lane >> 4)) ^ (r & 7);
                    av2[m] = *(const short8*)&sA[0][r * 64 + g * 8];
                }
                const int kb = kk + (lane >> 4) * 8;
                const float4 b0 = *(const float4*)&Bias[b * 64 + kb];
                const float4 b1 = *(const float4*)&Bias[b * 64 + kb + 4];
                const float bb[8] = {b0.x, b0.y, b0.z, b0.w, b1.x, b1.y, b1.z, b1.w};
#pragma unroll
                for (int n = 0; n < 2; ++n) {
                    const int r = wc * 32 + n * 16 + (lane & 15);
                    const int g = ((kk >> 3) + (lane >> 4)) ^ (r & 7);
                    const short8 wv = *(const short8*)&sB[0][r * 64 + g * 8];
                    short8 sv;
#pragma unroll
                    for (int j = 0; j < 8; ++j) {
                        const float wf = bf2f((ushort)wv[j]);
                        sv[j] = (short)f2bf(fmaxf(wf + bb[j], 0.f) - fmaxf(bb[j], 0.f));
                    }
                    bw[n] = sv;
                }
#pragma unroll
                for (int m = 0; m < 2; ++m)
#pragma unroll
                    for (int n = 0; n < 2; ++n)
                        acc[m][n] = __builtin_amdgcn_mfma_f32_16x16x32_bf16(
                            av2[m], bw[n], acc[m][n], 0, 0, 0);
            }
        }
    }

    // C/D layout: col = lane&15, row = (lane>>4)*4 + reg   [m89/m91 verified]
#pragma unroll
    for (int m = 0; m < 2; ++m)
#pragma unroll
        for (int n = 0; n < 2; ++n) {
            const int srow = s0 + wr * 32 + m * 16 + (lane >> 4) * 4;
            const int icol = i0 + wc * 32 + n * 16 + (lane & 15);
#pragma unroll
            for (int r = 0; r < 4; ++r)
                outp[(size_t)(srow + r) * INN + icol] = acc[m][n][r];
        }
}

// ---------------------------------------------------------------------------
extern "C" void kernel_launch(void* const* d_in, const int* in_sizes, int n_in,
                              void* d_out, int out_size, void* d_ws, size_t ws_size,
                              hipStream_t stream) {
    const float* uA    = (const float*)d_in[0];
    const float* W     = (const float*)d_in[1];
    const float* Bias  = (const float*)d_in[2];
    const float* Lb    = (const float*)d_in[3];
    const float* Ub    = (const float*)d_in[4];
    const float* Alpha = (const float*)d_in[5];
    float* outp = (float*)d_out;

    char* ws = (char*)d_ws;
    unsigned long long* rowmask = (unsigned long long*)ws;       // 4 KB
    ushort* A1 = (ushort*)(ws + 4096);                           // 4 MB
    ushort* A2 = (ushort*)(ws + 4096 + (1u << 22));              // 4 MB
    ushort* WT = (ushort*)(ws + 4096 + (2u << 22));              // 32 MB

    prep<<<4608, 256, 0, stream>>>(uA, W, Bias, Lb, Ub, Alpha, A1, A2, WT,
                                   rowmask, outp + (size_t)SPECN * INN);
    gemm<<<512, 256, 0, stream>>>(A1, A2, WT, Bias, rowmask, outp);
}